// Round 14
// baseline (211.975 us; speedup 1.0000x reference)
//
#include <hip/hip_runtime.h>
#include <stdint.h>

// ---------------------------------------------------------------------------
// HAN forward on MI355X (gfx950).  R14: fixes R13's LDS packing bug (B half
// was at +16KB instead of +8KB, doubling per-buffer LDS to 32KB and capping
// occupancy at 2 blocks/CU).  Now ring-2 x 16KB = 32KB total -> with VGPR=52
// the 512-thread/8-wave blocks reach 4 blocks/CU = 32 waves/CU (2x R12).
// Rest identical to R12/R13 (deferred softmax, fused logits, PV, fc-32).
// ---------------------------------------------------------------------------

typedef short s16x8 __attribute__((ext_vector_type(8)));
typedef float f32x4 __attribute__((ext_vector_type(4)));

#define ASYNC_CP16(gsrc, ldst)                                                  \
  __builtin_amdgcn_global_load_lds(                                             \
      (const __attribute__((address_space(1))) void*)(gsrc),                    \
      (__attribute__((address_space(3))) void*)(ldst), 16, 0, 0)

__device__ __forceinline__ float bfr2f(uint16_t u) {
  return __builtin_bit_cast(float, (uint32_t)u << 16);
}
__device__ __forceinline__ uint16_t f2bfr(float f) {
  uint32_t u = __builtin_bit_cast(uint32_t, f);
  u += 0x7fffu + ((u >> 16) & 1u);   // RNE
  return (uint16_t)(u >> 16);
}

// ---------------- merged conversion kernel (pad300 x4 + watt + fc_w) --------
__global__ __launch_bounds__(256) void cvt_all(
    const float* __restrict__ emb_f, const float* __restrict__ wk_f,
    const float* __restrict__ wq_f, const float* __restrict__ glove_f,
    const float* __restrict__ watt_f, const float* __restrict__ fc_f,
    uint16_t* __restrict__ EMB, uint16_t* __restrict__ WK,
    uint16_t* __restrict__ WQ, uint16_t* __restrict__ GLV,
    uint16_t* __restrict__ WATT, uint16_t* __restrict__ WFC) {
  const int idx = blockIdx.x * 256 + threadIdx.x;
  const int TOT1 = 61264 * 80;           // pad300 region
  const int TOT2 = TOT1 + 1024;          // watt region
  if (idx < TOT1) {
    const int row = idx / 80, j = idx % 80;
    const float* src;
    uint16_t* dst;
    int srow, svalid;
    if (row < 50000) {
      src = emb_f; dst = EMB; srow = row; svalid = 1;
    } else if (row < 53072) {
      src = wk_f; dst = WK; srow = row - 50000; svalid = 1;
    } else if (row < 56144) {
      src = wq_f; dst = WQ; srow = row - 53072; svalid = 1;
    } else {
      src = glove_f; dst = GLV; srow = row - 56144; svalid = (srow < 5000);
    }
    float4 v = make_float4(0.f, 0.f, 0.f, 0.f);
    if (svalid && j < 75) v = *(const float4*)(src + (size_t)srow * 300 + j * 4);
    ushort4 o;
    o.x = f2bfr(v.x); o.y = f2bfr(v.y); o.z = f2bfr(v.z); o.w = f2bfr(v.w);
    *(ushort4*)(dst + (size_t)srow * 320 + j * 4) = o;
  } else if (idx < TOT2) {
    const int i = idx - TOT1;  // < 1024
    float4 a = *(const float4*)(watt_f + i * 8);
    float4 b = *(const float4*)(watt_f + i * 8 + 4);
    ushort4 o0, o1;
    o0.x = f2bfr(a.x); o0.y = f2bfr(a.y); o0.z = f2bfr(a.z); o0.w = f2bfr(a.w);
    o1.x = f2bfr(b.x); o1.y = f2bfr(b.y); o1.z = f2bfr(b.z); o1.w = f2bfr(b.w);
    *(ushort4*)(WATT + i * 8) = o0;
    *(ushort4*)(WATT + i * 8 + 4) = o1;
  } else {
    const int i4 = idx - TOT2;  // < 384*2048
    if (i4 < 384 * 2048) {
      const int pos = i4 * 4;
      const int r = pos >> 13, c = pos & 8191;
      float4 v = make_float4(0.f, 0.f, 0.f, 0.f);
      if (r < 300) v = *(const float4*)(fc_f + (size_t)r * 8192 + c);
      ushort4 o;
      o.x = f2bfr(v.x); o.y = f2bfr(v.y); o.z = f2bfr(v.z); o.w = f2bfr(v.w);
      *(ushort4*)(WFC + (size_t)r * 8192 + c) = o;
    }
  }
}

// ============ gather-GEMM, 8 waves x 512 thr, 32KB LDS, 4 blocks/CU =========
// C[128m][1024] = gather(emb,he)@W^T + b,  K=960 (3 nodes x 320), BK=32.
// Ring-2 x 16KB packed (A[128][32] @ +0, B[128][32] @ +8KB), 2-barrier
// K-step, steady vmcnt(2).  Each wave owns 64x32 output: acc[4][2] (VGPR~52).
__global__ __launch_bounds__(512, 8) void gemm_gather512(
    const int* __restrict__ heK, const int* __restrict__ heQ,
    const uint16_t* __restrict__ emb,
    const uint16_t* __restrict__ WKp, const uint16_t* __restrict__ WQp,
    const float* __restrict__ bK, const float* __restrict__ bQ,
    uint16_t* __restrict__ HS, uint16_t* __restrict__ HQ) {
  __shared__ uint16_t ring[2 * 8192];  // 2 bufs x (A 8KB + B 8KB) = 32KB
  char* ringB = (char*)ring;

  const int t = threadIdx.x;
  const int lane = t & 63, wave = t >> 6;
  const int wr = wave >> 2, wq2 = wave & 3;      // wr: m-half, wq2: n-quarter
  const int fr = lane & 15, fq = lane >> 4;
  const int srow = t >> 2, skg = t & 3;          // srow 0..127
  const int skg2 = skg ^ ((srow >> 1) & 3);      // inverse LDS swizzle on src

  // bijective XCD-chunk swizzle; grid = (8, 272), nwg = 2176
  const int v = blockIdx.x + 8 * blockIdx.y;
  const int w = (v & 7) * 272 + (v >> 3);
  const int bx = w & 7, by = w >> 3;
  const int n0 = bx * 128;
  const bool isK = by < 256;
  const int m0 = (isK ? by : by - 256) * 128;
  const int* he = isK ? heK : heQ;
  const uint16_t* W = isK ? WKp : WQp;
  const float* bias = isK ? bK : bQ;
  uint16_t* C = isK ? HS : HQ;

  // per-thread staging offsets: A row (m0+srow), B row (n0+srow)
  uint32_t ea[3];
#pragma unroll
  for (int nd = 0; nd < 3; nd++)
    ea[nd] = (uint32_t)he[(long)(m0 + srow) * 3 + nd] * 640u +
             (uint32_t)(skg2 * 16);
  const uint16_t* Wr = W + (long)(n0 + srow) * 960 + skg2 * 8;

  f32x4 zv = {0.f, 0.f, 0.f, 0.f};
  f32x4 acc[4][2];
#pragma unroll
  for (int i = 0; i < 4; i++)
#pragma unroll
    for (int j = 0; j < 2; j++) acc[i][j] = zv;

  int snd = 0, skk = 0, sk = 0, sbuf = 0;
  auto STAGE = [&]() {
    const int bb = sbuf * 16384;   // 16KB per buffer (packed)
    const uint32_t e0 = snd == 0 ? ea[0] : (snd == 1 ? ea[1] : ea[2]);
    ASYNC_CP16((const char*)emb + e0 + skk * 64, ringB + bb + t * 16);
    ASYNC_CP16(Wr + sk, ringB + bb + 8192 + t * 16);
    sk += 32;
    if (++skk == 10) { skk = 0; ++snd; }
    sbuf ^= 1;
  };

  STAGE();  // stage step 0 into buf 0

  // lane-constant swizzled fragment bases (elements); mi/ni via immediates
  const int fsw = (fq ^ ((fr >> 1) & 3)) * 8;
  const int aof = (wr * 64 + fr) * 32 + fsw;             // + mi*512
  const int bof = 4096 + (wq2 * 32 + fr) * 32 + fsw;     // + ni*512

  int cbuf = 0;
  for (int kt = 0; kt < 30; ++kt) {
    if (kt < 29) {
      STAGE();  // stage step kt+1 into the other buffer
      asm volatile("s_waitcnt vmcnt(2)" ::: "memory");
    } else {
      asm volatile("s_waitcnt vmcnt(0)" ::: "memory");
    }
    __builtin_amdgcn_s_barrier();
    asm volatile("" ::: "memory");
    const uint16_t* base = ring + cbuf * 8192;
    s16x8 af[4], bv[2];
#pragma unroll
    for (int mi = 0; mi < 4; mi++)
      af[mi] = *(const s16x8*)(base + aof + mi * 512);
#pragma unroll
    for (int ni = 0; ni < 2; ni++)
      bv[ni] = *(const s16x8*)(base + bof + ni * 512);
    __builtin_amdgcn_s_setprio(1);
#pragma unroll
    for (int mi = 0; mi < 4; mi++)
#pragma unroll
      for (int ni = 0; ni < 2; ni++)
        acc[mi][ni] = __builtin_amdgcn_mfma_f32_16x16x32_bf16(
            af[mi], bv[ni], acc[mi][ni], 0, 0, 0);
    __builtin_amdgcn_s_setprio(0);
    asm volatile("s_waitcnt lgkmcnt(0)" ::: "memory");
    __builtin_amdgcn_s_barrier();
    cbuf ^= 1;
  }

  // epilogue: C = acc + bias
#pragma unroll
  for (int ni = 0; ni < 2; ni++) {
    const int gn = n0 + wq2 * 32 + ni * 16 + fr;
    const float bval = bias[gn];
#pragma unroll
    for (int mi = 0; mi < 4; mi++) {
      const int gmb = m0 + wr * 64 + mi * 16 + fq * 4;
      uint16_t* cp = C + (long)gmb * 1024 + gn;
      cp[0]    = f2bfr(acc[mi][ni][0] + bval);
      cp[1024] = f2bfr(acc[mi][ni][1] + bval);
      cp[2048] = f2bfr(acc[mi][ni][2] + bval);
      cp[3072] = f2bfr(acc[mi][ni][3] + bval);
    }
  }
}

// ============ fused logits GEMM: att_e = exp((hq (x) W_h) @ hs^T) ===========
__global__ __launch_bounds__(256) void gemm_logits(
    const uint16_t* __restrict__ hq, const uint16_t* __restrict__ watt,
    const uint16_t* __restrict__ hs, uint16_t* __restrict__ att,
    float* __restrict__ psum) {
  __shared__ uint16_t ring[3 * 4096];  // 3 x B[128][32]
  __shared__ float sSum[8][2];
  char* ringB = (char*)ring;

  const int t = threadIdx.x;
  const int lane = t & 63, wave = t >> 6;
  const int wr = wave >> 1, wc = wave & 1;
  const int fr = lane & 15, fq = lane >> 4;
  const int srow = t >> 2, skg = t & 3;
  const int skg2 = skg ^ ((srow >> 1) & 3);

  // bijective XCD swizzle; nwg = 2*128 = 256
  int bx = blockIdx.x, bz = blockIdx.z;
  {
    const int v = bx + 2 * bz;
    const int w = (v & 7) * 32 + (v >> 3);
    bx = w & 1;
    bz = w >> 1;
  }
  const int n0 = bx * 128;

  const uint16_t* Bs0 = hs + (long)bz * 262144 + (long)(n0 + srow) * 1024 + skg2 * 8;
  const uint16_t* Bs1 = hs + (long)bz * 262144 + (long)(n0 + 64 + srow) * 1024 + skg2 * 8;
  const uint16_t* hqp = hq + (long)(bz * 16 + fr) * 1024 + fq * 8;
  const uint16_t* wp0 = watt + (long)(wr * 4 + 0) * 1024 + fq * 8;
  const uint16_t* wp1 = watt + (long)(wr * 4 + 1) * 1024 + fq * 8;
  const uint16_t* wp2 = watt + (long)(wr * 4 + 2) * 1024 + fq * 8;
  const uint16_t* wp3 = watt + (long)(wr * 4 + 3) * 1024 + fq * 8;

  f32x4 zv = {0.f, 0.f, 0.f, 0.f};
  f32x4 acc[4][4];
#pragma unroll
  for (int i = 0; i < 4; i++)
#pragma unroll
    for (int j = 0; j < 4; j++) acc[i][j] = zv;

  int sbuf = 0, cbuf = 0;
  ASYNC_CP16(Bs0, ringB + t * 16);
  ASYNC_CP16(Bs1, ringB + 2048 + t * 16);
  ASYNC_CP16(Bs0 + 32, ringB + 4096 + t * 16);
  ASYNC_CP16(Bs1 + 32, ringB + 4096 + 2048 + t * 16);
  sbuf = 2;
  s16x8 hqA = *(const s16x8*)(hqp);
  s16x8 wA0 = *(const s16x8*)(wp0), wA1 = *(const s16x8*)(wp1);
  s16x8 wA2 = *(const s16x8*)(wp2), wA3 = *(const s16x8*)(wp3);
  s16x8 hqB, wB0, wB1, wB2, wB3;

  const int fsw = (fq ^ ((fr >> 1) & 3)) * 8;
  int bof[4];
#pragma unroll
  for (int ni = 0; ni < 4; ni++)
    bof[ni] = (wc * 64 + ni * 16 + fr) * 32 + fsw;

#define LOG_BODY(KT, HQS, W0S, W1S, W2S, W3S, HQD, W0D, W1D, W2D, W3D)          \
  {                                                                             \
    const int kt = (KT);                                                        \
    if (kt + 2 < 32) {                                                          \
      ASYNC_CP16(Bs0 + (kt + 2) * 32, ringB + sbuf * 4096 + t * 16);            \
      ASYNC_CP16(Bs1 + (kt + 2) * 32, ringB + sbuf * 4096 + 2048 + t * 16);     \
      if (++sbuf == 3) sbuf = 0;                                                \
    }                                                                           \
    if (kt + 1 < 32) {                                                          \
      const int ko = (kt + 1) * 32;                                             \
      HQD = *(const s16x8*)(hqp + ko);                                          \
      W0D = *(const s16x8*)(wp0 + ko); W1D = *(const s16x8*)(wp1 + ko);         \
      W2D = *(const s16x8*)(wp2 + ko); W3D = *(const s16x8*)(wp3 + ko);         \
    }                                                                           \
    asm volatile("s_waitcnt vmcnt(7)" ::: "memory");                            \
    __builtin_amdgcn_s_barrier();                                               \
    asm volatile("" ::: "memory");                                              \
    s16x8 af0, af1, af2, af3, bv[4];                                            \
    _Pragma("unroll") for (int j = 0; j < 8; j++) {                             \
      const float hv = bfr2f((uint16_t)HQS[j]);                                 \
      af0[j] = (short)f2bfr(hv * bfr2f((uint16_t)W0S[j]));                      \
      af1[j] = (short)f2bfr(hv * bfr2f((uint16_t)W1S[j]));                      \
      af2[j] = (short)f2bfr(hv * bfr2f((uint16_t)W2S[j]));                      \
      af3[j] = (short)f2bfr(hv * bfr2f((uint16_t)W3S[j]));                      \
    }                                                                           \
    const uint16_t* base = ring + cbuf * 4096;                                  \
    _Pragma("unroll") for (int ni = 0; ni < 4; ni++)                            \
        bv[ni] = *(const s16x8*)(base + bof[ni]);                               \
    __builtin_amdgcn_s_setprio(1);                                              \
    _Pragma("unroll") for (int ni = 0; ni < 4; ni++) {                          \
      acc[0][ni] = __builtin_amdgcn_mfma_f32_16x16x32_bf16(af0, bv[ni],         \
                                                           acc[0][ni], 0, 0, 0);\
      acc[1][ni] = __builtin_amdgcn_mfma_f32_16x16x32_bf16(af1, bv[ni],         \
                                                           acc[1][ni], 0, 0, 0);\
      acc[2][ni] = __builtin_amdgcn_mfma_f32_16x16x32_bf16(af2, bv[ni],         \
                                                           acc[2][ni], 0, 0, 0);\
      acc[3][ni] = __builtin_amdgcn_mfma_f32_16x16x32_bf16(af3, bv[ni],         \
                                                           acc[3][ni], 0, 0, 0);\
    }                                                                           \
    __builtin_amdgcn_s_setprio(0);                                              \
    asm volatile("s_waitcnt lgkmcnt(0)" ::: "memory");                          \
    __builtin_amdgcn_s_barrier();                                               \
    if (++cbuf == 3) cbuf = 0;                                                  \
  }

  for (int kt2 = 0; kt2 < 32; kt2 += 2) {
    LOG_BODY(kt2, hqA, wA0, wA1, wA2, wA3, hqB, wB0, wB1, wB2, wB3);
    LOG_BODY(kt2 + 1, hqB, wB0, wB1, wB2, wB3, hqA, wA0, wA1, wA2, wA3);
  }
#undef LOG_BODY

  // exponentiate + per-(h, wc) wave sums
#pragma unroll
  for (int mi = 0; mi < 4; mi++) {
    float s = 0.f;
#pragma unroll
    for (int ni = 0; ni < 4; ni++)
#pragma unroll
      for (int j = 0; j < 4; j++) {
        const float e = __expf(acc[mi][ni][j]);
        acc[mi][ni][j] = e;
        s += e;
      }
#pragma unroll
    for (int d = 1; d < 64; d <<= 1) s += __shfl_xor(s, d);
    if (lane == 0) sSum[wr * 4 + mi][wc] = s;
  }
  __syncthreads();
  if (t < 8) psum[((long)bz * 8 + t) * 2 + bx] = sSum[t][0] + sSum[t][1];

  // store unnormalized e (bf16)
#pragma unroll
  for (int ni = 0; ni < 4; ni++) {
    const int gn = n0 + wc * 64 + ni * 16 + fr;
#pragma unroll
    for (int mi = 0; mi < 4; mi++)
#pragma unroll
      for (int j = 0; j < 4; j++) {
        const int gm = wr * 64 + mi * 16 + fq * 4 + j;
        att[(long)bz * 32768 + gm * 256 + gn] = f2bfr(acc[mi][ni][j]);
      }
  }
}

// ============ pipelined plain GEMM (fc / sim): Cf = A @ Bt^T ================
template <int SWZ>
__global__ __launch_bounds__(256) void gemm_pipe(
    const uint16_t* __restrict__ A, int lda, long sAb,
    const uint16_t* __restrict__ Bt, int ldb, long sBb,
    int ksteps, int kchunk,
    float* __restrict__ Cf, int ldcf, int nmax, long sCf) {
  __shared__ uint16_t ring[3 * 8192];
  char* ringB = (char*)ring;

  const int t = threadIdx.x;
  const int lane = t & 63, wave = t >> 6;
  const int wr = wave >> 1, wc = wave & 1;
  const int fr = lane & 15, fq = lane >> 4;
  const int srow = t >> 2, skg = t & 3;
  const int skg2 = skg ^ ((srow >> 1) & 3);

  int bx = blockIdx.x, bz = blockIdx.z;
  if (SWZ) {
    const int nwg = gridDim.x * gridDim.z;
    const int v = bx + gridDim.x * bz;
    const int w = (v & 7) * (nwg >> 3) + (v >> 3);
    bx = w % gridDim.x;
    bz = w / gridDim.x;
  }
  const int m0 = blockIdx.y * 128, n0 = bx * 128;
  const uint16_t* Ab = A + (long)bz * sAb;
  const uint16_t* Bb = Bt;

  f32x4 zv = {0.f, 0.f, 0.f, 0.f};
  f32x4 acc[4][4];
#pragma unroll
  for (int i = 0; i < 4; i++)
#pragma unroll
    for (int j = 0; j < 4; j++) acc[i][j] = zv;

  const long kbase = (long)bz * kchunk;
  const uint16_t* As0 = Ab + (long)(m0 + srow) * lda + kbase + skg2 * 8;
  const uint16_t* As1 = Ab + (long)(m0 + 64 + srow) * lda + kbase + skg2 * 8;
  const uint16_t* Bs0 = Bb + (long)(n0 + srow) * ldb + kbase + skg2 * 8;
  const uint16_t* Bs1 = Bb + (long)(n0 + 64 + srow) * ldb + kbase + skg2 * 8;

  int sk = 0, sbuf = 0;
  auto STAGE = [&]() {
    const int bb = sbuf * 16384;
    ASYNC_CP16(As0 + sk, ringB + bb + t * 16);
    ASYNC_CP16(As1 + sk, ringB + bb + 4096 + t * 16);
    ASYNC_CP16(Bs0 + sk, ringB + bb + 8192 + t * 16);
    ASYNC_CP16(Bs1 + sk, ringB + bb + 12288 + t * 16);
    sk += 32;
    if (++sbuf == 3) sbuf = 0;
  };

  STAGE();
  STAGE();

  const int fsw = (fq ^ ((fr >> 1) & 3)) * 8;
  int aof[4], bof[4];
#pragma unroll
  for (int mi = 0; mi < 4; mi++) aof[mi] = (wr * 64 + mi * 16 + fr) * 32 + fsw;
#pragma unroll
  for (int ni = 0; ni < 4; ni++)
    bof[ni] = 4096 + (wc * 64 + ni * 16 + fr) * 32 + fsw;

  int cbuf = 0;
  for (int kt = 0; kt < ksteps; ++kt) {
    if (kt + 2 < ksteps) STAGE();
    if (kt + 2 < ksteps)      asm volatile("s_waitcnt vmcnt(8)" ::: "memory");
    else if (kt + 1 < ksteps) asm volatile("s_waitcnt vmcnt(4)" ::: "memory");
    else                      asm volatile("s_waitcnt vmcnt(0)" ::: "memory");
    __builtin_amdgcn_s_barrier();
    asm volatile("" ::: "memory");
    const uint16_t* base = ring + cbuf * 8192;
    s16x8 af[4], bv[4];
#pragma unroll
    for (int mi = 0; mi < 4; mi++) af[mi] = *(const s16x8*)(base + aof[mi]);
#pragma unroll
    for (int ni = 0; ni < 4; ni++) bv[ni] = *(const s16x8*)(base + bof[ni]);
#pragma unroll
    for (int mi = 0; mi < 4; mi++)
#pragma unroll
      for (int ni = 0; ni < 4; ni++)
        acc[mi][ni] = __builtin_amdgcn_mfma_f32_16x16x32_bf16(
            af[mi], bv[ni], acc[mi][ni], 0, 0, 0);
    asm volatile("s_waitcnt lgkmcnt(0)" ::: "memory");
    __builtin_amdgcn_s_barrier();
    if (++cbuf == 3) cbuf = 0;
  }

#pragma unroll
  for (int ni = 0; ni < 4; ni++) {
    const int gn = n0 + wc * 64 + ni * 16 + fr;
    if (gn < nmax) {
#pragma unroll
      for (int mi = 0; mi < 4; mi++)
#pragma unroll
        for (int j = 0; j < 4; j++) {
          const int gm = m0 + wr * 64 + mi * 16 + fq * 4 + j;
          Cf[(long)bz * sCf + (long)gm * ldcf + gn] = acc[mi][ni][j];
        }
    }
  }
}

// ============ PV GEMM with in-LDS hs transpose + fused pooled + 1/S ========
__global__ __launch_bounds__(256) void gemm_pv(
    const uint16_t* __restrict__ att, const uint16_t* __restrict__ hs,
    const uint16_t* __restrict__ hqp, const float* __restrict__ psum,
    uint16_t* __restrict__ pooled) {
  __shared__ uint16_t sT[128 * 264];
  __shared__ uint16_t sA[4096];
  __shared__ uint16_t sHq[2048];

  const int t = threadIdx.x;
  const int lane = t & 63, wave = t >> 6;
  const int wr = wave >> 1, wc = wave & 1;
  const int fr = lane & 15, fq = lane >> 4;
  const int srow = t >> 2, skg = t & 3;
  const int skg2 = skg ^ ((srow >> 1) & 3);

  int bx = blockIdx.x, bz = blockIdx.z;
  {
    const int v = bx + 8 * bz;
    const int w = (v & 7) * 128 + (v >> 3);
    bx = w & 7;
    bz = w >> 3;
  }
  const int n0 = bx * 128;

  const uint16_t* hsb = hs + (long)bz * 262144;
  const int sloc = t & 15, c8 = t >> 4;
  s16x8 vv[16];
#pragma unroll
  for (int p = 0; p < 16; p++)
    vv[p] = *(const s16x8*)(hsb + (long)(p * 16 + sloc) * 1024 + n0 + c8 * 8);
  *(s16x8*)(sHq + (t >> 4) * 128 + (t & 15) * 8) =
      *(const s16x8*)(hqp + (long)bz * 16384 + (long)(t >> 4) * 1024 + n0 +
                      (t & 15) * 8);
#pragma unroll
  for (int p = 0; p < 16; p++) {
    const int s = p * 16 + sloc;
#pragma unroll
    for (int j = 0; j < 8; j++)
      sT[(c8 * 8 + j) * 264 + s] = (uint16_t)vv[p][j];
  }
  __syncthreads();

  f32x4 zv = {0.f, 0.f, 0.f, 0.f};
  f32x4 acc[4][4];
#pragma unroll
  for (int i = 0; i < 4; i++)
#pragma unroll
    for (int j = 0; j < 4; j++) acc[i][j] = zv;

  const uint16_t* As0 = att + (long)bz * 32768 + (long)srow * 256 + skg2 * 8;
  const uint16_t* As1 = att + (long)bz * 32768 + (long)(64 + srow) * 256 + skg2 * 8;

  const int fsw = (fq ^ ((fr >> 1) & 3)) * 8;
  int aof[4];
#pragma unroll
  for (int mi = 0; mi < 4; mi++) aof[mi] = (wr * 64 + mi * 16 + fr) * 32 + fsw;

  for (int kt = 0; kt < 8; ++kt) {
    ASYNC_CP16(As0 + kt * 32, (char*)sA + t * 16);
    ASYNC_CP16(As1 + kt * 32, (char*)sA + 4096 + t * 16);
    __syncthreads();
    s16x8 af[4], bv[4];
#pragma unroll
    for (int mi = 0; mi < 4; mi++) af[mi] = *(const s16x8*)(sA + aof[mi]);
#pragma unroll
    for (int ni = 0; ni < 4; ni++)
      bv[ni] = *(const s16x8*)(sT + (wc * 64 + ni * 16 + fr) * 264 + kt * 32 +
                               fq * 8);
    __builtin_amdgcn_s_setprio(1);
#pragma unroll
    for (int mi = 0; mi < 4; mi++)
#pragma unroll
      for (int ni = 0; ni < 4; ni++)
        acc[mi][ni] = __builtin_amdgcn_mfma_f32_16x16x32_bf16(
            af[mi], bv[ni], acc[mi][ni], 0, 0, 0);
    __builtin_amdgcn_s_setprio(0);
    __syncthreads();
  }

#pragma unroll
  for (int mi = 0; mi < 4; mi++) {
    const int hh = wr * 4 + mi;
    const float ri = 1.f / (psum[((long)bz * 8 + hh) * 2] +
                            psum[((long)bz * 8 + hh) * 2 + 1]);
#pragma unroll
    for (int ni = 0; ni < 4; ni++) {
      const int col = wc * 64 + ni * 16 + fr;
      float p = 0.f;
#pragma unroll
      for (int j = 0; j < 4; j++)
        p += acc[mi][ni][j] * bfr2f(sHq[(fq * 4 + j) * 128 + col]);
      p += __shfl_xor(p, 16);
      p += __shfl_xor(p, 32);
      if (fq == 0)
        pooled[(long)bz * 8192 + hh * 1024 + n0 + col] = f2bfr(p * ri);
    }
  }
}

// ---------------- fc partial-sum (32 chunks) + bias -> bf16 padded -----------
__global__ __launch_bounds__(256) void cvt_out_k(const float* __restrict__ parts,
                                                 const float* __restrict__ fc_b,
                                                 uint16_t* __restrict__ outb) {
  int idx = blockIdx.x * 256 + threadIdx.x;
  if (idx >= 128 * 320) return;
  int m = idx / 320, n = idx % 320;
  float v = 0.f;
  if (n < 300) {
    v = fc_b[n];
#pragma unroll
    for (int ch = 0; ch < 32; ch++) v += parts[ch * 38400 + m * 300 + n];
  }
  outb[idx] = f2bfr(v);
}

// ---------------- row log-softmax over 5000 ----------------
__global__ __launch_bounds__(256) void logsoftmax_k(const float* __restrict__ sim,
                                                    float* __restrict__ out) {
  const int r = blockIdx.x, t = threadIdx.x;
  __shared__ float red[4];
  __shared__ float red2[4];
  const float* x = sim + (long)r * 5000;
  float mx = -1e30f;
  for (int i = t; i < 5000; i += 256) mx = fmaxf(mx, x[i]);
#pragma unroll
  for (int d = 1; d < 64; d <<= 1) mx = fmaxf(mx, __shfl_xor(mx, d));
  if ((t & 63) == 0) red[t >> 6] = mx;
  __syncthreads();
  mx = fmaxf(fmaxf(red[0], red[1]), fmaxf(red[2], red[3]));
  float s = 0.f;
  for (int i = t; i < 5000; i += 256) s += __expf(x[i] - mx);
#pragma unroll
  for (int d = 1; d < 64; d <<= 1) s += __shfl_xor(s, d);
  if ((t & 63) == 0) red2[t >> 6] = s;
  __syncthreads();
  s = red2[0] + red2[1] + red2[2] + red2[3];
  const float lse = mx + logf(s);
  float* o = out + (long)r * 5000;
  for (int i = t; i < 5000; i += 256) o[i] = x[i] - lse;
}

// ---------------------------------------------------------------------------
extern "C" void kernel_launch(void* const* d_in, const int* in_sizes, int n_in,
                              void* d_out, int out_size, void* d_ws, size_t ws_size,
                              hipStream_t stream) {
  (void)in_sizes; (void)n_in; (void)out_size; (void)ws_size;
  const int* he_q = (const int*)d_in[0];
  const int* he_k = (const int*)d_in[1];
  const float* emb_f = (const float*)d_in[2];
  const float* q2h_w = (const float*)d_in[3];
  const float* q2h_b = (const float*)d_in[4];
  const float* k2h_w = (const float*)d_in[5];
  const float* k2h_b = (const float*)d_in[6];
  const float* h2att_w = (const float*)d_in[7];
  // d_in[8] = h2att_b: uniform per-head shift, softmax-invariant -> unused
  const float* fc_w = (const float*)d_in[9];
  const float* fc_b = (const float*)d_in[10];
  const float* glove = (const float*)d_in[11];
  float* out = (float*)d_out;

  char* ws = (char*)d_ws;
  uint16_t* EMB   = (uint16_t*)(ws);              // 50000x320 bf16   32,000,000
  uint16_t* WK    = (uint16_t*)(ws + 32000000);   // 3072x320         1,966,080
  uint16_t* WQ    = (uint16_t*)(ws + 33966080);   // 3072x320         1,966,080
  uint16_t* WATT  = (uint16_t*)(ws + 35932160);   // 8x1024              16,384
  uint16_t* WFC   = (uint16_t*)(ws + 35948544);   // 384x8192         6,291,456
  uint16_t* GLV   = (uint16_t*)(ws + 42240000);   // 5120x320         3,276,800
  uint16_t* HQ    = (uint16_t*)(ws + 45516800);   // 2048x1024        4,194,304
  uint16_t* HS    = (uint16_t*)(ws + 49711104);   // 32768x1024      67,108,864
  uint16_t* ATT   = (uint16_t*)(ws + 183928832);  // 128x128x256      8,388,608
  uint16_t* POOL  = (uint16_t*)(ws + 192317440);  // 128x8192         2,097,152
  uint16_t* OUTB  = (uint16_t*)(ws + 195643392);  // 128x320             81,920
  float*    SIM   = (float*)(ws + 195725312);     // 128x5000 f32     2,560,000
  float*    PARTS = (float*)(ws + 49711104);      // 32x128x300 f32 (dead HS)
  float*    PSUM  = (float*)(ws);                 // 128x8x2 f32 (dead EMB)

  // 1) conversions (single merged kernel: pad300 x4 + watt + fc_w)
  cvt_all<<<22221, 256, 0, stream>>>(emb_f, k2h_w, q2h_w, glove, h2att_w, fc_w,
                                     EMB, WK, WQ, GLV, WATT, WFC);

  // 2) projections: 8-wave 512-thread blocks, 32KB LDS, 32 waves/CU
  gemm_gather512<<<dim3(8, 272), 512, 0, stream>>>(
      he_k, he_q, EMB, WK, WQ, k2h_b, q2h_b, HS, HQ);

  // 3) fused logits -> e=exp(logit) in ATT + per-(b,h) partial sums in PSUM
  gemm_logits<<<dim3(2, 1, 128), 256, 0, stream>>>(HQ, WATT, HS, ATT, PSUM);

  // 4) PV + pooled + deferred softmax normalization (x 1/S)
  gemm_pv<<<dim3(8, 1, 128), 256, 0, stream>>>(ATT, HS, HQ, PSUM, POOL);

  // 5) fc split-K (32 chunks of 256) -> 96 blocks
  gemm_pipe<0><<<dim3(3, 1, 32), 256, 0, stream>>>(
      POOL, 8192, 0, WFC, 8192, 0, 8, 256, PARTS, 300, 300, 38400);

  // 6) sum partials + fc_b -> bf16 padded
  cvt_out_k<<<160, 256, 0, stream>>>(PARTS, fc_b, OUTB);

  // 7) sim = out @ glove^T
  gemm_pipe<0><<<dim3(40, 1, 1), 256, 0, stream>>>(
      OUTB, 320, 0, GLV, 320, 0, 10, 0, SIM, 5000, 5000, 0);

  // 8) log-softmax
  logsoftmax_k<<<128, 256, 0, stream>>>(SIM, out);
}

// Round 15
// 188.972 us; speedup vs baseline: 1.1217x; 1.1217x over previous
//
#include <hip/hip_runtime.h>
#include <stdint.h>

// ---------------------------------------------------------------------------
// HAN forward on MI355X (gfx950).  R15: full revert to R12's proven kernel
// set (gather = ring-2 / 4-wave / 16 waves/CU, 97us champion; R13/R14 proved
// both bigger barrier groups and higher occupancy REGRESS this latency-bound
// structure).  One tail change: gemm_logits n-tile 128->64 (512 blocks,
// 2 blocks/CU, 8 waves/CU vs 4), ring 3x4KB, counted vmcnt(6), psum x4.
// ---------------------------------------------------------------------------

typedef short s16x8 __attribute__((ext_vector_type(8)));
typedef float f32x4 __attribute__((ext_vector_type(4)));

#define ASYNC_CP16(gsrc, ldst)                                                  \
  __builtin_amdgcn_global_load_lds(                                             \
      (const __attribute__((address_space(1))) void*)(gsrc),                    \
      (__attribute__((address_space(3))) void*)(ldst), 16, 0, 0)

__device__ __forceinline__ float bfr2f(uint16_t u) {
  return __builtin_bit_cast(float, (uint32_t)u << 16);
}
__device__ __forceinline__ uint16_t f2bfr(float f) {
  uint32_t u = __builtin_bit_cast(uint32_t, f);
  u += 0x7fffu + ((u >> 16) & 1u);   // RNE
  return (uint16_t)(u >> 16);
}

// ---------------- merged conversion kernel (pad300 x4 + watt + fc_w) --------
__global__ __launch_bounds__(256) void cvt_all(
    const float* __restrict__ emb_f, const float* __restrict__ wk_f,
    const float* __restrict__ wq_f, const float* __restrict__ glove_f,
    const float* __restrict__ watt_f, const float* __restrict__ fc_f,
    uint16_t* __restrict__ EMB, uint16_t* __restrict__ WK,
    uint16_t* __restrict__ WQ, uint16_t* __restrict__ GLV,
    uint16_t* __restrict__ WATT, uint16_t* __restrict__ WFC) {
  const int idx = blockIdx.x * 256 + threadIdx.x;
  const int TOT1 = 61264 * 80;           // pad300 region
  const int TOT2 = TOT1 + 1024;          // watt region
  if (idx < TOT1) {
    const int row = idx / 80, j = idx % 80;
    const float* src;
    uint16_t* dst;
    int srow, svalid;
    if (row < 50000) {
      src = emb_f; dst = EMB; srow = row; svalid = 1;
    } else if (row < 53072) {
      src = wk_f; dst = WK; srow = row - 50000; svalid = 1;
    } else if (row < 56144) {
      src = wq_f; dst = WQ; srow = row - 53072; svalid = 1;
    } else {
      src = glove_f; dst = GLV; srow = row - 56144; svalid = (srow < 5000);
    }
    float4 v = make_float4(0.f, 0.f, 0.f, 0.f);
    if (svalid && j < 75) v = *(const float4*)(src + (size_t)srow * 300 + j * 4);
    ushort4 o;
    o.x = f2bfr(v.x); o.y = f2bfr(v.y); o.z = f2bfr(v.z); o.w = f2bfr(v.w);
    *(ushort4*)(dst + (size_t)srow * 320 + j * 4) = o;
  } else if (idx < TOT2) {
    const int i = idx - TOT1;  // < 1024
    float4 a = *(const float4*)(watt_f + i * 8);
    float4 b = *(const float4*)(watt_f + i * 8 + 4);
    ushort4 o0, o1;
    o0.x = f2bfr(a.x); o0.y = f2bfr(a.y); o0.z = f2bfr(a.z); o0.w = f2bfr(a.w);
    o1.x = f2bfr(b.x); o1.y = f2bfr(b.y); o1.z = f2bfr(b.z); o1.w = f2bfr(b.w);
    *(ushort4*)(WATT + i * 8) = o0;
    *(ushort4*)(WATT + i * 8 + 4) = o1;
  } else {
    const int i4 = idx - TOT2;  // < 384*2048
    if (i4 < 384 * 2048) {
      const int pos = i4 * 4;
      const int r = pos >> 13, c = pos & 8191;
      float4 v = make_float4(0.f, 0.f, 0.f, 0.f);
      if (r < 300) v = *(const float4*)(fc_f + (size_t)r * 8192 + c);
      ushort4 o;
      o.x = f2bfr(v.x); o.y = f2bfr(v.y); o.z = f2bfr(v.z); o.w = f2bfr(v.w);
      *(ushort4*)(WFC + (size_t)r * 8192 + c) = o;
    }
  }
}

// ============ pipelined gather-GEMM (ring-2, no sIdx LDS): hs + hq ==========
// C[128m][1024] = gather(emb,he)@W^T + b,  K=960 (3 nodes x 320), BK=32.
// LDS = exactly 32KB -> 4 blocks/CU.  Per-lane he reads from global (L2-hot).
__global__ __launch_bounds__(256) void gemm_gather2(
    const int* __restrict__ heK, const int* __restrict__ heQ,
    const uint16_t* __restrict__ emb,
    const uint16_t* __restrict__ WKp, const uint16_t* __restrict__ WQp,
    const float* __restrict__ bK, const float* __restrict__ bQ,
    uint16_t* __restrict__ HS, uint16_t* __restrict__ HQ) {
  __shared__ uint16_t ring[2 * 8192];  // 2 bufs x (A[128][32] + B[128][32])
  char* ringB = (char*)ring;

  const int t = threadIdx.x;
  const int lane = t & 63, wave = t >> 6;
  const int wr = wave >> 1, wc = wave & 1;
  const int fr = lane & 15, fq = lane >> 4;
  const int srow = t >> 2, skg = t & 3;
  const int skg2 = skg ^ ((srow >> 1) & 3);  // inverse LDS swizzle on source

  // bijective XCD-chunk swizzle; grid = (8, 272), nwg = 2176
  const int v = blockIdx.x + 8 * blockIdx.y;
  const int w = (v & 7) * 272 + (v >> 3);
  const int bx = w & 7, by = w >> 3;
  const int n0 = bx * 128;
  const bool isK = by < 256;
  const int m0 = (isK ? by : by - 256) * 128;
  const int* he = isK ? heK : heQ;
  const uint16_t* W = isK ? WKp : WQp;
  const float* bias = isK ? bK : bQ;
  uint16_t* C = isK ? HS : HQ;

  // per-lane staging offsets straight from global he (6 L2-hot int loads)
  uint32_t ea[2][3];
#pragma unroll
  for (int h = 0; h < 2; h++)
#pragma unroll
    for (int nd = 0; nd < 3; nd++)
      ea[h][nd] = (uint32_t)he[(long)(m0 + h * 64 + srow) * 3 + nd] * 640u +
                  (uint32_t)(skg2 * 16);
  const uint16_t* Wr0 = W + (long)(n0 + srow) * 960 + skg2 * 8;
  const uint16_t* Wr1 = W + (long)(n0 + 64 + srow) * 960 + skg2 * 8;

  f32x4 zv = {0.f, 0.f, 0.f, 0.f};
  f32x4 acc[4][4];
#pragma unroll
  for (int i = 0; i < 4; i++)
#pragma unroll
    for (int j = 0; j < 4; j++) acc[i][j] = zv;

  int snd = 0, skk = 0, sk = 0, sbuf = 0;
  auto STAGE = [&]() {
    const int bb = sbuf * 16384;
    const uint32_t e0 = snd == 0 ? ea[0][0] : (snd == 1 ? ea[0][1] : ea[0][2]);
    const uint32_t e1 = snd == 0 ? ea[1][0] : (snd == 1 ? ea[1][1] : ea[1][2]);
    ASYNC_CP16((const char*)emb + e0 + skk * 64, ringB + bb + t * 16);
    ASYNC_CP16((const char*)emb + e1 + skk * 64, ringB + bb + 4096 + t * 16);
    ASYNC_CP16(Wr0 + sk, ringB + bb + 8192 + t * 16);
    ASYNC_CP16(Wr1 + sk, ringB + bb + 12288 + t * 16);
    sk += 32;
    if (++skk == 10) { skk = 0; ++snd; }
    sbuf ^= 1;
  };

  STAGE();  // stage step 0 into buf 0

  const int fsw = (fq ^ ((fr >> 1) & 3)) * 8;
  int aof[4], bof[4];
#pragma unroll
  for (int mi = 0; mi < 4; mi++) aof[mi] = (wr * 64 + mi * 16 + fr) * 32 + fsw;
#pragma unroll
  for (int ni = 0; ni < 4; ni++)
    bof[ni] = 4096 + (wc * 64 + ni * 16 + fr) * 32 + fsw;

  int cbuf = 0;
  for (int kt = 0; kt < 30; ++kt) {
    if (kt < 29) {
      STAGE();  // stage step kt+1 into the other buffer
      asm volatile("s_waitcnt vmcnt(4)" ::: "memory");
    } else {
      asm volatile("s_waitcnt vmcnt(0)" ::: "memory");
    }
    __builtin_amdgcn_s_barrier();
    asm volatile("" ::: "memory");
    const uint16_t* base = ring + cbuf * 8192;
    s16x8 af[4], bv[4];
#pragma unroll
    for (int mi = 0; mi < 4; mi++) af[mi] = *(const s16x8*)(base + aof[mi]);
#pragma unroll
    for (int ni = 0; ni < 4; ni++) bv[ni] = *(const s16x8*)(base + bof[ni]);
    __builtin_amdgcn_s_setprio(1);
#pragma unroll
    for (int mi = 0; mi < 4; mi++)
#pragma unroll
      for (int ni = 0; ni < 4; ni++)
        acc[mi][ni] = __builtin_amdgcn_mfma_f32_16x16x32_bf16(
            af[mi], bv[ni], acc[mi][ni], 0, 0, 0);
    __builtin_amdgcn_s_setprio(0);
    asm volatile("s_waitcnt lgkmcnt(0)" ::: "memory");
    __builtin_amdgcn_s_barrier();
    cbuf ^= 1;
  }

#pragma unroll
  for (int ni = 0; ni < 4; ni++) {
    const int gn = n0 + wc * 64 + ni * 16 + fr;
    const float bval = bias[gn];
#pragma unroll
    for (int mi = 0; mi < 4; mi++) {
      const int gmb = m0 + wr * 64 + mi * 16 + fq * 4;
      uint16_t* cp = C + (long)gmb * 1024 + gn;
      cp[0]    = f2bfr(acc[mi][ni][0] + bval);
      cp[1024] = f2bfr(acc[mi][ni][1] + bval);
      cp[2048] = f2bfr(acc[mi][ni][2] + bval);
      cp[3072] = f2bfr(acc[mi][ni][3] + bval);
    }
  }
}

// ============ fused logits GEMM, n-tile 64: att_e = exp((hq (x) W_h)@hs^T) ==
// grid (4,1,128) = 512 blocks (2/CU).  Waves: wr = m-half (h=wr*4+mi),
// wc = n-half-of-64.  acc[4][2].  Ring 3 x 4KB, 1 CP16/thread/step,
// uniform counted vmcnt(6).  psum[bz][h][bx] (4 partials per (b,h)).
__global__ __launch_bounds__(256) void gemm_logits(
    const uint16_t* __restrict__ hq, const uint16_t* __restrict__ watt,
    const uint16_t* __restrict__ hs, uint16_t* __restrict__ att,
    float* __restrict__ psum) {
  __shared__ uint16_t ring[3 * 2048];  // 3 x B[64][32]
  __shared__ float sSum[8][2];
  char* ringB = (char*)ring;

  const int t = threadIdx.x;
  const int lane = t & 63, wave = t >> 6;
  const int wr = wave >> 1, wc = wave & 1;
  const int fr = lane & 15, fq = lane >> 4;
  const int srow = t >> 2, skg = t & 3;       // srow 0..63
  const int skg2 = skg ^ ((srow >> 1) & 3);

  // bijective XCD swizzle; nwg = 4*128 = 512
  int bx = blockIdx.x, bz = blockIdx.z;
  {
    const int v = bx + 4 * bz;
    const int w = (v & 7) * 64 + (v >> 3);
    bx = w & 3;
    bz = w >> 2;
  }
  const int n0 = bx * 64;

  const uint16_t* Bs0 = hs + (long)bz * 262144 + (long)(n0 + srow) * 1024 + skg2 * 8;
  const uint16_t* hqp = hq + (long)(bz * 16 + fr) * 1024 + fq * 8;
  const uint16_t* wp0 = watt + (long)(wr * 4 + 0) * 1024 + fq * 8;
  const uint16_t* wp1 = watt + (long)(wr * 4 + 1) * 1024 + fq * 8;
  const uint16_t* wp2 = watt + (long)(wr * 4 + 2) * 1024 + fq * 8;
  const uint16_t* wp3 = watt + (long)(wr * 4 + 3) * 1024 + fq * 8;

  f32x4 zv = {0.f, 0.f, 0.f, 0.f};
  f32x4 acc[4][2];
#pragma unroll
  for (int i = 0; i < 4; i++)
#pragma unroll
    for (int j = 0; j < 2; j++) acc[i][j] = zv;

  int sbuf = 0, cbuf = 0;
  ASYNC_CP16(Bs0, ringB + t * 16);
  ASYNC_CP16(Bs0 + 32, ringB + 4096 + t * 16);
  sbuf = 2;
  s16x8 hqA = *(const s16x8*)(hqp);
  s16x8 wA0 = *(const s16x8*)(wp0), wA1 = *(const s16x8*)(wp1);
  s16x8 wA2 = *(const s16x8*)(wp2), wA3 = *(const s16x8*)(wp3);
  s16x8 hqB, wB0, wB1, wB2, wB3;

  const int fsw = (fq ^ ((fr >> 1) & 3)) * 8;
  int bof[2];
#pragma unroll
  for (int ni = 0; ni < 2; ni++)
    bof[ni] = (wc * 32 + ni * 16 + fr) * 32 + fsw;

#define LOG_BODY(KT, HQS, W0S, W1S, W2S, W3S, HQD, W0D, W1D, W2D, W3D)          \
  {                                                                             \
    const int kt = (KT);                                                        \
    if (kt + 2 < 32) {                                                          \
      ASYNC_CP16(Bs0 + (kt + 2) * 32, ringB + sbuf * 4096 + t * 16);            \
      if (++sbuf == 3) sbuf = 0;                                                \
    }                                                                           \
    if (kt + 1 < 32) {                                                          \
      const int ko = (kt + 1) * 32;                                             \
      HQD = *(const s16x8*)(hqp + ko);                                          \
      W0D = *(const s16x8*)(wp0 + ko); W1D = *(const s16x8*)(wp1 + ko);         \
      W2D = *(const s16x8*)(wp2 + ko); W3D = *(const s16x8*)(wp3 + ko);         \
    }                                                                           \
    asm volatile("s_waitcnt vmcnt(6)" ::: "memory");                            \
    __builtin_amdgcn_s_barrier();                                               \
    asm volatile("" ::: "memory");                                              \
    s16x8 af0, af1, af2, af3, bv[2];                                            \
    _Pragma("unroll") for (int j = 0; j < 8; j++) {                             \
      const float hv = bfr2f((uint16_t)HQS[j]);                                 \
      af0[j] = (short)f2bfr(hv * bfr2f((uint16_t)W0S[j]));                      \
      af1[j] = (short)f2bfr(hv * bfr2f((uint16_t)W1S[j]));                      \
      af2[j] = (short)f2bfr(hv * bfr2f((uint16_t)W2S[j]));                      \
      af3[j] = (short)f2bfr(hv * bfr2f((uint16_t)W3S[j]));                      \
    }                                                                           \
    const uint16_t* base = ring + cbuf * 2048;                                  \
    _Pragma("unroll") for (int ni = 0; ni < 2; ni++)                            \
        bv[ni] = *(const s16x8*)(base + bof[ni]);                               \
    __builtin_amdgcn_s_setprio(1);                                              \
    _Pragma("unroll") for (int ni = 0; ni < 2; ni++) {                          \
      acc[0][ni] = __builtin_amdgcn_mfma_f32_16x16x32_bf16(af0, bv[ni],         \
                                                           acc[0][ni], 0, 0, 0);\
      acc[1][ni] = __builtin_amdgcn_mfma_f32_16x16x32_bf16(af1, bv[ni],         \
                                                           acc[1][ni], 0, 0, 0);\
      acc[2][ni] = __builtin_amdgcn_mfma_f32_16x16x32_bf16(af2, bv[ni],         \
                                                           acc[2][ni], 0, 0, 0);\
      acc[3][ni] = __builtin_amdgcn_mfma_f32_16x16x32_bf16(af3, bv[ni],         \
                                                           acc[3][ni], 0, 0, 0);\
    }                                                                           \
    __builtin_amdgcn_s_setprio(0);                                              \
    asm volatile("s_waitcnt lgkmcnt(0)" ::: "memory");                          \
    __builtin_amdgcn_s_barrier();                                               \
    if (++cbuf == 3) cbuf = 0;                                                  \
  }

  for (int kt2 = 0; kt2 < 32; kt2 += 2) {
    LOG_BODY(kt2, hqA, wA0, wA1, wA2, wA3, hqB, wB0, wB1, wB2, wB3);
    LOG_BODY(kt2 + 1, hqB, wB0, wB1, wB2, wB3, hqA, wA0, wA1, wA2, wA3);
  }
#undef LOG_BODY

  // exponentiate + per-(h, wc) wave sums
#pragma unroll
  for (int mi = 0; mi < 4; mi++) {
    float s = 0.f;
#pragma unroll
    for (int ni = 0; ni < 2; ni++)
#pragma unroll
      for (int j = 0; j < 4; j++) {
        const float e = __expf(acc[mi][ni][j]);
        acc[mi][ni][j] = e;
        s += e;
      }
#pragma unroll
    for (int d = 1; d < 64; d <<= 1) s += __shfl_xor(s, d);
    if (lane == 0) sSum[wr * 4 + mi][wc] = s;
  }
  __syncthreads();
  if (t < 8) psum[((long)bz * 8 + t) * 4 + bx] = sSum[t][0] + sSum[t][1];

  // store unnormalized e (bf16)
#pragma unroll
  for (int ni = 0; ni < 2; ni++) {
    const int gn = n0 + wc * 32 + ni * 16 + fr;
#pragma unroll
    for (int mi = 0; mi < 4; mi++)
#pragma unroll
      for (int j = 0; j < 4; j++) {
        const int gm = wr * 64 + mi * 16 + fq * 4 + j;
        att[(long)bz * 32768 + gm * 256 + gn] = f2bfr(acc[mi][ni][j]);
      }
  }
}

// ============ pipelined plain GEMM (fc / sim): Cf = A @ Bt^T ================
template <int SWZ>
__global__ __launch_bounds__(256) void gemm_pipe(
    const uint16_t* __restrict__ A, int lda, long sAb,
    const uint16_t* __restrict__ Bt, int ldb, long sBb,
    int ksteps, int kchunk,
    float* __restrict__ Cf, int ldcf, int nmax, long sCf) {
  __shared__ uint16_t ring[3 * 8192];
  char* ringB = (char*)ring;

  const int t = threadIdx.x;
  const int lane = t & 63, wave = t >> 6;
  const int wr = wave >> 1, wc = wave & 1;
  const int fr = lane & 15, fq = lane >> 4;
  const int srow = t >> 2, skg = t & 3;
  const int skg2 = skg ^ ((srow >> 1) & 3);

  int bx = blockIdx.x, bz = blockIdx.z;
  if (SWZ) {
    const int nwg = gridDim.x * gridDim.z;
    const int v = bx + gridDim.x * bz;
    const int w = (v & 7) * (nwg >> 3) + (v >> 3);
    bx = w % gridDim.x;
    bz = w / gridDim.x;
  }
  const int m0 = blockIdx.y * 128, n0 = bx * 128;
  const uint16_t* Ab = A + (long)bz * sAb;
  const uint16_t* Bb = Bt;

  f32x4 zv = {0.f, 0.f, 0.f, 0.f};
  f32x4 acc[4][4];
#pragma unroll
  for (int i = 0; i < 4; i++)
#pragma unroll
    for (int j = 0; j < 4; j++) acc[i][j] = zv;

  const long kbase = (long)bz * kchunk;
  const uint16_t* As0 = Ab + (long)(m0 + srow) * lda + kbase + skg2 * 8;
  const uint16_t* As1 = Ab + (long)(m0 + 64 + srow) * lda + kbase + skg2 * 8;
  const uint16_t* Bs0 = Bb + (long)(n0 + srow) * ldb + kbase + skg2 * 8;
  const uint16_t* Bs1 = Bb + (long)(n0 + 64 + srow) * ldb + kbase + skg2 * 8;

  int sk = 0, sbuf = 0;
  auto STAGE = [&]() {
    const int bb = sbuf * 16384;
    ASYNC_CP16(As0 + sk, ringB + bb + t * 16);
    ASYNC_CP16(As1 + sk, ringB + bb + 4096 + t * 16);
    ASYNC_CP16(Bs0 + sk, ringB + bb + 8192 + t * 16);
    ASYNC_CP16(Bs1 + sk, ringB + bb + 12288 + t * 16);
    sk += 32;
    if (++sbuf == 3) sbuf = 0;
  };

  STAGE();
  STAGE();

  const int fsw = (fq ^ ((fr >> 1) & 3)) * 8;
  int aof[4], bof[4];
#pragma unroll
  for (int mi = 0; mi < 4; mi++) aof[mi] = (wr * 64 + mi * 16 + fr) * 32 + fsw;
#pragma unroll
  for (int ni = 0; ni < 4; ni++)
    bof[ni] = 4096 + (wc * 64 + ni * 16 + fr) * 32 + fsw;

  int cbuf = 0;
  for (int kt = 0; kt < ksteps; ++kt) {
    if (kt + 2 < ksteps) STAGE();
    if (kt + 2 < ksteps)      asm volatile("s_waitcnt vmcnt(8)" ::: "memory");
    else if (kt + 1 < ksteps) asm volatile("s_waitcnt vmcnt(4)" ::: "memory");
    else                      asm volatile("s_waitcnt vmcnt(0)" ::: "memory");
    __builtin_amdgcn_s_barrier();
    asm volatile("" ::: "memory");
    const uint16_t* base = ring + cbuf * 8192;
    s16x8 af[4], bv[4];
#pragma unroll
    for (int mi = 0; mi < 4; mi++) af[mi] = *(const s16x8*)(base + aof[mi]);
#pragma unroll
    for (int ni = 0; ni < 4; ni++) bv[ni] = *(const s16x8*)(base + bof[ni]);
#pragma unroll
    for (int mi = 0; mi < 4; mi++)
#pragma unroll
      for (int ni = 0; ni < 4; ni++)
        acc[mi][ni] = __builtin_amdgcn_mfma_f32_16x16x32_bf16(
            af[mi], bv[ni], acc[mi][ni], 0, 0, 0);
    asm volatile("s_waitcnt lgkmcnt(0)" ::: "memory");
    __builtin_amdgcn_s_barrier();
    if (++cbuf == 3) cbuf = 0;
  }

#pragma unroll
  for (int ni = 0; ni < 4; ni++) {
    const int gn = n0 + wc * 64 + ni * 16 + fr;
    if (gn < nmax) {
#pragma unroll
      for (int mi = 0; mi < 4; mi++)
#pragma unroll
        for (int j = 0; j < 4; j++) {
          const int gm = m0 + wr * 64 + mi * 16 + fq * 4 + j;
          Cf[(long)bz * sCf + (long)gm * ldcf + gn] = acc[mi][ni][j];
        }
    }
  }
}

// ============ PV GEMM with in-LDS hs transpose + fused pooled + 1/S ========
__global__ __launch_bounds__(256) void gemm_pv(
    const uint16_t* __restrict__ att, const uint16_t* __restrict__ hs,
    const uint16_t* __restrict__ hqp, const float* __restrict__ psum,
    uint16_t* __restrict__ pooled) {
  __shared__ uint16_t sT[128 * 264];
  __shared__ uint16_t sA[4096];
  __shared__ uint16_t sHq[2048];

  const int t = threadIdx.x;
  const int lane = t & 63, wave = t >> 6;
  const int wr = wave >> 1, wc = wave & 1;
  const int fr = lane & 15, fq = lane >> 4;
  const int srow = t >> 2, skg = t & 3;
  const int skg2 = skg ^ ((srow >> 1) & 3);

  int bx = blockIdx.x, bz = blockIdx.z;
  {
    const int v = bx + 8 * bz;
    const int w = (v & 7) * 128 + (v >> 3);
    bx = w & 7;
    bz = w >> 3;
  }
  const int n0 = bx * 128;

  const uint16_t* hsb = hs + (long)bz * 262144;
  const int sloc = t & 15, c8 = t >> 4;
  s16x8 vv[16];
#pragma unroll
  for (int p = 0; p < 16; p++)
    vv[p] = *(const s16x8*)(hsb + (long)(p * 16 + sloc) * 1024 + n0 + c8 * 8);
  *(s16x8*)(sHq + (t >> 4) * 128 + (t & 15) * 8) =
      *(const s16x8*)(hqp + (long)bz * 16384 + (long)(t >> 4) * 1024 + n0 +
                      (t & 15) * 8);
#pragma unroll
  for (int p = 0; p < 16; p++) {
    const int s = p * 16 + sloc;
#pragma unroll
    for (int j = 0; j < 8; j++)
      sT[(c8 * 8 + j) * 264 + s] = (uint16_t)vv[p][j];
  }
  __syncthreads();

  f32x4 zv = {0.f, 0.f, 0.f, 0.f};
  f32x4 acc[4][4];
#pragma unroll
  for (int i = 0; i < 4; i++)
#pragma unroll
    for (int j = 0; j < 4; j++) acc[i][j] = zv;

  const uint16_t* As0 = att + (long)bz * 32768 + (long)srow * 256 + skg2 * 8;
  const uint16_t* As1 = att + (long)bz * 32768 + (long)(64 + srow) * 256 + skg2 * 8;

  const int fsw = (fq ^ ((fr >> 1) & 3)) * 8;
  int aof[4];
#pragma unroll
  for (int mi = 0; mi < 4; mi++) aof[mi] = (wr * 64 + mi * 16 + fr) * 32 + fsw;

  for (int kt = 0; kt < 8; ++kt) {
    ASYNC_CP16(As0 + kt * 32, (char*)sA + t * 16);
    ASYNC_CP16(As1 + kt * 32, (char*)sA + 4096 + t * 16);
    __syncthreads();
    s16x8 af[4], bv[4];
#pragma unroll
    for (int mi = 0; mi < 4; mi++) af[mi] = *(const s16x8*)(sA + aof[mi]);
#pragma unroll
    for (int ni = 0; ni < 4; ni++)
      bv[ni] = *(const s16x8*)(sT + (wc * 64 + ni * 16 + fr) * 264 + kt * 32 +
                               fq * 8);
    __builtin_amdgcn_s_setprio(1);
#pragma unroll
    for (int mi = 0; mi < 4; mi++)
#pragma unroll
      for (int ni = 0; ni < 4; ni++)
        acc[mi][ni] = __builtin_amdgcn_mfma_f32_16x16x32_bf16(
            af[mi], bv[ni], acc[mi][ni], 0, 0, 0);
    __builtin_amdgcn_s_setprio(0);
    __syncthreads();
  }

#pragma unroll
  for (int mi = 0; mi < 4; mi++) {
    const int hh = wr * 4 + mi;
    const float* ps = psum + ((long)bz * 8 + hh) * 4;
    const float ri = 1.f / (ps[0] + ps[1] + ps[2] + ps[3]);
#pragma unroll
    for (int ni = 0; ni < 4; ni++) {
      const int col = wc * 64 + ni * 16 + fr;
      float p = 0.f;
#pragma unroll
      for (int j = 0; j < 4; j++)
        p += acc[mi][ni][j] * bfr2f(sHq[(fq * 4 + j) * 128 + col]);
      p += __shfl_xor(p, 16);
      p += __shfl_xor(p, 32);
      if (fq == 0)
        pooled[(long)bz * 8192 + hh * 1024 + n0 + col] = f2bfr(p * ri);
    }
  }
}

// ---------------- fc partial-sum (32 chunks) + bias -> bf16 padded -----------
__global__ __launch_bounds__(256) void cvt_out_k(const float* __restrict__ parts,
                                                 const float* __restrict__ fc_b,
                                                 uint16_t* __restrict__ outb) {
  int idx = blockIdx.x * 256 + threadIdx.x;
  if (idx >= 128 * 320) return;
  int m = idx / 320, n = idx % 320;
  float v = 0.f;
  if (n < 300) {
    v = fc_b[n];
#pragma unroll
    for (int ch = 0; ch < 32; ch++) v += parts[ch * 38400 + m * 300 + n];
  }
  outb[idx] = f2bfr(v);
}

// ---------------- row log-softmax over 5000 ----------------
__global__ __launch_bounds__(256) void logsoftmax_k(const float* __restrict__ sim,
                                                    float* __restrict__ out) {
  const int r = blockIdx.x, t = threadIdx.x;
  __shared__ float red[4];
  __shared__ float red2[4];
  const float* x = sim + (long)r * 5000;
  float mx = -1e30f;
  for (int i = t; i < 5000; i += 256) mx = fmaxf(mx, x[i]);
#pragma unroll
  for (int d = 1; d < 64; d <<= 1) mx = fmaxf(mx, __shfl_xor(mx, d));
  if ((t & 63) == 0) red[t >> 6] = mx;
  __syncthreads();
  mx = fmaxf(fmaxf(red[0], red[1]), fmaxf(red[2], red[3]));
  float s = 0.f;
  for (int i = t; i < 5000; i += 256) s += __expf(x[i] - mx);
#pragma unroll
  for (int d = 1; d < 64; d <<= 1) s += __shfl_xor(s, d);
  if ((t & 63) == 0) red2[t >> 6] = s;
  __syncthreads();
  s = red2[0] + red2[1] + red2[2] + red2[3];
  const float lse = mx + logf(s);
  float* o = out + (long)r * 5000;
  for (int i = t; i < 5000; i += 256) o[i] = x[i] - lse;
}

// ---------------------------------------------------------------------------
extern "C" void kernel_launch(void* const* d_in, const int* in_sizes, int n_in,
                              void* d_out, int out_size, void* d_ws, size_t ws_size,
                              hipStream_t stream) {
  (void)in_sizes; (void)n_in; (void)out_size; (void)ws_size;
  const int* he_q = (const int*)d_in[0];
  const int* he_k = (const int*)d_in[1];
  const float* emb_f = (const float*)d_in[2];
  const float* q2h_w = (const float*)d_in[3];
  const float* q2h_b = (const float*)d_in[4];
  const float* k2h_w = (const float*)d_in[5];
  const float* k2h_b = (const float*)d_in[6];
  const float* h2att_w = (const float*)d_in[7];
  // d_in[8] = h2att_b: uniform per-head shift, softmax-invariant -> unused
  const float* fc_w = (const float*)d_in[9];
  const float* fc_b = (const float*)d_in[10];
  const float* glove = (const float*)d_in[11];
  float* out = (float*)d_out;

  char* ws = (char*)d_ws;
  uint16_t* EMB   = (uint16_t*)(ws);              // 50000x320 bf16   32,000,000
  uint16_t* WK    = (uint16_t*)(ws + 32000000);   // 3072x320         1,966,080
  uint16_t* WQ    = (uint16_t*)(ws + 33966080);   // 3072x320         1,966,080
  uint16_t* WATT  = (uint16_t*)(ws + 35932160);   // 8x1024              16,384
  uint16_t* WFC   = (uint16_t*)(ws + 35948544);   // 384x8192         6,291,456
  uint16_t* GLV   = (uint16_t*)(ws + 42240000);   // 5120x320         3,276,800
  uint16_t* HQ    = (uint16_t*)(ws + 45516800);   // 2048x1024        4,194,304
  uint16_t* HS    = (uint16_t*)(ws + 49711104);   // 32768x1024      67,108,864
  uint16_t* ATT   = (uint16_t*)(ws + 183928832);  // 128x128x256      8,388,608
  uint16_t* POOL  = (uint16_t*)(ws + 192317440);  // 128x8192         2,097,152
  uint16_t* OUTB  = (uint16_t*)(ws + 195643392);  // 128x320             81,920
  float*    SIM   = (float*)(ws + 195725312);     // 128x5000 f32     2,560,000
  float*    PARTS = (float*)(ws + 49711104);      // 32x128x300 f32 (dead HS)
  float*    PSUM  = (float*)(ws);                 // 128x8x4 f32 (dead EMB)

  // 1) conversions (single merged kernel: pad300 x4 + watt + fc_w)
  cvt_all<<<22221, 256, 0, stream>>>(emb_f, k2h_w, q2h_w, glove, h2att_w, fc_w,
                                     EMB, WK, WQ, GLV, WATT, WFC);

  // 2) projections: hs and hq in ONE pipelined launch (ring-2, 4 blocks/CU)
  gemm_gather2<<<dim3(8, 272), 256, 0, stream>>>(
      he_k, he_q, EMB, WK, WQ, k2h_b, q2h_b, HS, HQ);

  // 3) fused logits -> e=exp(logit) in ATT + per-(b,h,quarter) sums in PSUM
  gemm_logits<<<dim3(4, 1, 128), 256, 0, stream>>>(HQ, WATT, HS, ATT, PSUM);

  // 4) PV + pooled + deferred softmax normalization (x 1/S)
  gemm_pv<<<dim3(8, 1, 128), 256, 0, stream>>>(ATT, HS, HQ, PSUM, POOL);

  // 5) fc split-K (32 chunks of 256) -> 96 blocks
  gemm_pipe<0><<<dim3(3, 1, 32), 256, 0, stream>>>(
      POOL, 8192, 0, WFC, 8192, 0, 8, 256, PARTS, 300, 300, 38400);

  // 6) sum partials + fc_b -> bf16 padded
  cvt_out_k<<<160, 256, 0, stream>>>(PARTS, fc_b, OUTB);

  // 7) sim = out @ glove^T
  gemm_pipe<0><<<dim3(40, 1, 1), 256, 0, stream>>>(
      OUTB, 320, 0, GLV, 320, 0, 10, 0, SIM, 5000, 5000, 0);

  // 8) log-softmax
  logsoftmax_k<<<128, 256, 0, stream>>>(SIM, out);
}